// Round 7
// baseline (72.948 us; speedup 1.0000x reference)
//
#include <hip/hip_runtime.h>

// ClassCaps vote transform:
//   votes[b,h,w,i,o,m,p] = sum_n poses[b,h,w,i,m,n] * weight[i,o,n,p]
//                          + (m==0&&p==3 ? xv[h,w] : 0) + (m==1&&p==3 ? yv[h,w] : 0)
// Outputs (concatenated): votes [B*H*W*CIN*COUT*16] fp32, acts [B*H*W*CIN] fp32.
//
// 1280 blocks (5/CU, all co-resident, zero tail, trip count exactly 49).
// f4-stride = 327680 -> site-step = 8192: (i,o,m) loop-invariant, weights in
// registers; hw advances +60 mod 196 incrementally. This round:
//  - depth-4 rotating-register pose pipeline (4 loads in flight)
//  - nontemporal loads/stores via clang ext_vector float4 (HIP_vector_type
//    is rejected by __builtin_nontemporal_*)

typedef float vf4 __attribute__((ext_vector_type(4)));

namespace {
constexpr int kCIN = 32, kCOUT = 10, kHW = 14 * 14;
constexpr int kSITES = 64 * kHW * kCIN;            // 401408
constexpr int kVotesF4 = kSITES * kCOUT * 4;       // 16,056,320 float4s
constexpr int kVotesFloats = kVotesF4 * 4;
constexpr int kVoteBlocks = 1280;                  // 5 blocks/CU exactly
constexpr int kThreads = kVoteBlocks * 256;        // 327,680 = f4 grid stride
constexpr int kSiteStep = kThreads / (kCOUT * 4);  // 8192 sites per iter
constexpr int kPStep = kSiteStep * 4;              // pose float4s per iter
constexpr int kHwStep = (kSiteStep >> 5) % kHW;    // 60
constexpr int kIters = kVotesF4 / kThreads;        // 49 (exact)
constexpr int kMain = kIters - 4;                  // 45 = 15 x unroll(3)
constexpr int kActsF4 = kSITES / 4;                // 100352 = 392 * 256
constexpr int kActBlocks = kActsF4 / 256;          // 392
}

__device__ __forceinline__ vf4 vote_row(const vf4 p, const vf4 w0, const vf4 w1,
                                        const vf4 w2, const vf4 w3, const float cx) {
    vf4 r;
    r.x = fmaf(p.x, w0.x, fmaf(p.y, w1.x, fmaf(p.z, w2.x, p.w * w3.x)));
    r.y = fmaf(p.x, w0.y, fmaf(p.y, w1.y, fmaf(p.z, w2.y, p.w * w3.y)));
    r.z = fmaf(p.x, w0.z, fmaf(p.y, w1.z, fmaf(p.z, w2.z, p.w * w3.z)));
    r.w = fmaf(p.x, w0.w, fmaf(p.y, w1.w, fmaf(p.z, w2.w, p.w * w3.w))) + cx;
    return r;
}

__global__ __launch_bounds__(256) void classcaps_kernel(
    const vf4* __restrict__ poses,    // [kSITES*4]: row m of site at site*4+m
    const vf4* __restrict__ acts4,    // [kSITES/4]
    const vf4* __restrict__ weight4,  // [kCIN*kCOUT*4]: row n of (i,o)
    const float* __restrict__ xv,     // [196]
    const float* __restrict__ yv,     // [196]
    vf4*       __restrict__ out_votes,
    vf4*       __restrict__ out_acts)
{
    const int blk = blockIdx.x;
    const int tid = blk * 256 + threadIdx.x;

    // Activations pass-through, folded into the first 392 blocks (exact).
    if (blk < kActBlocks)
        __builtin_nontemporal_store(__builtin_nontemporal_load(acts4 + tid),
                                    out_acts + tid);

    const int m     = tid & 3;
    const int so    = tid >> 2;
    const int site0 = so / kCOUT;
    const int o     = so - site0 * kCOUT;
    const int i     = site0 & (kCIN - 1);
    int hw          = (site0 >> 5) % kHW;

    // Branchless coord source: m=0 -> xv, m=1 -> yv, m>=2 -> *0.
    const float* ctab = (m & 1) ? yv : xv;
    const float cmask = (m < 2) ? 1.0f : 0.0f;

    // Weight matrix for (i,o): 16 floats in registers, loaded once.
    const vf4* wr = weight4 + (i * kCOUT + o) * 4;
    const vf4 w0 = wr[0], w1 = wr[1], w2 = wr[2], w3 = wr[3];

    const vf4* pp = poses + site0 * 4 + m;
    vf4*       op = out_votes + tid;

    // Depth-4 rotating-register pipeline; exact 49-iteration trip.
    vf4 q0 = __builtin_nontemporal_load(pp);
    vf4 q1 = __builtin_nontemporal_load(pp + kPStep);
    vf4 q2 = __builtin_nontemporal_load(pp + 2 * kPStep);
    vf4 q3 = __builtin_nontemporal_load(pp + 3 * kPStep);
    pp += 4 * kPStep;
    float cx = ctab[hw] * cmask;                 // coord for iter 0

    #pragma unroll 3
    for (int k = 0; k < kMain; ++k) {            // iters 0..44
        const vf4 cur = q0;
        q0 = q1; q1 = q2; q2 = q3;
        q3 = __builtin_nontemporal_load(pp);     // prefetch iter k+4 (<= 48)
        pp += kPStep;
        const float c_cur = cx;
        hw += kHwStep; if (hw >= kHW) hw -= kHW; // advance to iter k+1
        cx = ctab[hw] * cmask;
        __builtin_nontemporal_store(vote_row(cur, w0, w1, w2, w3, c_cur), op);
        op += kThreads;
    }
    // Epilogue: iters 45..48 (statically indexed).
    __builtin_nontemporal_store(vote_row(q0, w0, w1, w2, w3, cx), op);
    op += kThreads;
    hw += kHwStep; if (hw >= kHW) hw -= kHW;
    cx = ctab[hw] * cmask;
    __builtin_nontemporal_store(vote_row(q1, w0, w1, w2, w3, cx), op);
    op += kThreads;
    hw += kHwStep; if (hw >= kHW) hw -= kHW;
    cx = ctab[hw] * cmask;
    __builtin_nontemporal_store(vote_row(q2, w0, w1, w2, w3, cx), op);
    op += kThreads;
    hw += kHwStep; if (hw >= kHW) hw -= kHW;
    cx = ctab[hw] * cmask;
    __builtin_nontemporal_store(vote_row(q3, w0, w1, w2, w3, cx), op);
}

extern "C" void kernel_launch(void* const* d_in, const int* in_sizes, int n_in,
                              void* d_out, int out_size, void* d_ws, size_t ws_size,
                              hipStream_t stream) {
    const vf4* poses   = (const vf4*)d_in[0];
    const vf4* acts4   = (const vf4*)d_in[1];
    const vf4* weight4 = (const vf4*)d_in[2];
    const float* xv    = (const float*)d_in[3];
    const float* yv    = (const float*)d_in[4];

    float* out = (float*)d_out;
    vf4* out_votes = (vf4*)out;
    vf4* out_acts  = (vf4*)(out + kVotesFloats);

    dim3 grid(kVoteBlocks), block(256);
    classcaps_kernel<<<grid, block, 0, stream>>>(
        poses, acts4, weight4, xv, yv, out_votes, out_acts);
}

// Round 8
// 51.363 us; speedup vs baseline: 1.4203x; 1.4203x over previous
//
#include <hip/hip_runtime.h>

// ClassCaps vote transform:
//   votes[b,h,w,i,o,m,p] = sum_n poses[b,h,w,i,m,n] * weight[i,o,n,p]
//                          + (m==0&&p==3 ? xv[h,w] : 0) + (m==1&&p==3 ? yv[h,w] : 0)
// Outputs (concatenated): votes [B*H*W*CIN*COUT*16] fp32, acts [B*H*W*CIN] fp32.
//
// 1280 blocks (5/CU, all co-resident, zero tail, trip 49 exact).
// (i,o,m) loop-invariant -> weights in registers; hw advances +60 mod 196.
// Round 8: REGULAR loads (poses have 10x reuse across o -> must cache;
// round 7's NT loads inflated FETCH ~10x), NT stores only (votes/acts are
// write-once streams; bypassing L2/L3 write-allocate was worth ~1.5x).

typedef float vf4 __attribute__((ext_vector_type(4)));

namespace {
constexpr int kCIN = 32, kCOUT = 10, kHW = 14 * 14;
constexpr int kSITES = 64 * kHW * kCIN;            // 401408
constexpr int kVotesF4 = kSITES * kCOUT * 4;       // 16,056,320 float4s
constexpr int kVotesFloats = kVotesF4 * 4;
constexpr int kVoteBlocks = 1280;                  // 5 blocks/CU exactly
constexpr int kThreads = kVoteBlocks * 256;        // 327,680 = f4 grid stride
constexpr int kSiteStep = kThreads / (kCOUT * 4);  // 8192 sites per iter
constexpr int kPStep = kSiteStep * 4;              // pose float4s per iter
constexpr int kHwStep = (kSiteStep >> 5) % kHW;    // 60
constexpr int kIters = kVotesF4 / kThreads;        // 49 (exact)
constexpr int kMain = kIters - 4;                  // 45 = 15 x unroll(3)
constexpr int kActsF4 = kSITES / 4;                // 100352 = 392 * 256
constexpr int kActBlocks = kActsF4 / 256;          // 392
}

__device__ __forceinline__ vf4 vote_row(const vf4 p, const vf4 w0, const vf4 w1,
                                        const vf4 w2, const vf4 w3, const float cx) {
    vf4 r;
    r.x = fmaf(p.x, w0.x, fmaf(p.y, w1.x, fmaf(p.z, w2.x, p.w * w3.x)));
    r.y = fmaf(p.x, w0.y, fmaf(p.y, w1.y, fmaf(p.z, w2.y, p.w * w3.y)));
    r.z = fmaf(p.x, w0.z, fmaf(p.y, w1.z, fmaf(p.z, w2.z, p.w * w3.z)));
    r.w = fmaf(p.x, w0.w, fmaf(p.y, w1.w, fmaf(p.z, w2.w, p.w * w3.w))) + cx;
    return r;
}

__global__ __launch_bounds__(256) void classcaps_kernel(
    const vf4* __restrict__ poses,    // [kSITES*4]: row m of site at site*4+m
    const vf4* __restrict__ acts4,    // [kSITES/4]
    const vf4* __restrict__ weight4,  // [kCIN*kCOUT*4]: row n of (i,o)
    const float* __restrict__ xv,     // [196]
    const float* __restrict__ yv,     // [196]
    vf4*       __restrict__ out_votes,
    vf4*       __restrict__ out_acts)
{
    const int blk = blockIdx.x;
    const int tid = blk * 256 + threadIdx.x;

    // Activations pass-through, folded into the first 392 blocks (exact).
    if (blk < kActBlocks)
        __builtin_nontemporal_store(acts4[tid], out_acts + tid);

    const int m     = tid & 3;
    const int so    = tid >> 2;
    const int site0 = so / kCOUT;
    const int o     = so - site0 * kCOUT;
    const int i     = site0 & (kCIN - 1);
    int hw          = (site0 >> 5) % kHW;

    // Branchless coord source: m=0 -> xv, m=1 -> yv, m>=2 -> *0.
    const float* ctab = (m & 1) ? yv : xv;
    const float cmask = (m < 2) ? 1.0f : 0.0f;

    // Weight matrix for (i,o): 16 floats in registers, loaded once.
    const vf4* wr = weight4 + (i * kCOUT + o) * 4;
    const vf4 w0 = wr[0], w1 = wr[1], w2 = wr[2], w3 = wr[3];

    const vf4* pp = poses + site0 * 4 + m;
    vf4*       op = out_votes + tid;

    // Depth-4 rotating-register pipeline; exact 49-iteration trip.
    vf4 q0 = pp[0];
    vf4 q1 = pp[kPStep];
    vf4 q2 = pp[2 * kPStep];
    vf4 q3 = pp[3 * kPStep];
    pp += 4 * kPStep;
    float cx = ctab[hw] * cmask;                 // coord for iter 0

    #pragma unroll 3
    for (int k = 0; k < kMain; ++k) {            // iters 0..44
        const vf4 cur = q0;
        q0 = q1; q1 = q2; q2 = q3;
        q3 = pp[0];                              // cached prefetch iter k+4
        pp += kPStep;
        const float c_cur = cx;
        hw += kHwStep; if (hw >= kHW) hw -= kHW; // advance to iter k+1
        cx = ctab[hw] * cmask;
        __builtin_nontemporal_store(vote_row(cur, w0, w1, w2, w3, c_cur), op);
        op += kThreads;
    }
    // Epilogue: iters 45..48 (statically indexed).
    __builtin_nontemporal_store(vote_row(q0, w0, w1, w2, w3, cx), op);
    op += kThreads;
    hw += kHwStep; if (hw >= kHW) hw -= kHW;
    cx = ctab[hw] * cmask;
    __builtin_nontemporal_store(vote_row(q1, w0, w1, w2, w3, cx), op);
    op += kThreads;
    hw += kHwStep; if (hw >= kHW) hw -= kHW;
    cx = ctab[hw] * cmask;
    __builtin_nontemporal_store(vote_row(q2, w0, w1, w2, w3, cx), op);
    op += kThreads;
    hw += kHwStep; if (hw >= kHW) hw -= kHW;
    cx = ctab[hw] * cmask;
    __builtin_nontemporal_store(vote_row(q3, w0, w1, w2, w3, cx), op);
}

extern "C" void kernel_launch(void* const* d_in, const int* in_sizes, int n_in,
                              void* d_out, int out_size, void* d_ws, size_t ws_size,
                              hipStream_t stream) {
    const vf4* poses   = (const vf4*)d_in[0];
    const vf4* acts4   = (const vf4*)d_in[1];
    const vf4* weight4 = (const vf4*)d_in[2];
    const float* xv    = (const float*)d_in[3];
    const float* yv    = (const float*)d_in[4];

    float* out = (float*)d_out;
    vf4* out_votes = (vf4*)out;
    vf4* out_acts  = (vf4*)(out + kVotesFloats);

    dim3 grid(kVoteBlocks), block(256);
    classcaps_kernel<<<grid, block, 0, stream>>>(
        poses, acts4, weight4, xv, yv, out_votes, out_acts);
}